// Round 2
// baseline (4445.427 us; speedup 1.0000x reference)
//
#include <hip/hip_runtime.h>

#define HID 2048
#define INTER 5632
#define KVW 256
#define NL 6
#define RMS_EPS 1e-6f

#define NB 512     // grid blocks (must equal 2 * 256 CUs for co-residency math)
#define NT 512     // threads per block (8 waves)
#define NLEAF 32
#define LEAF_N 16  // NB / NLEAF arrivals per leaf

typedef unsigned int uint;

// ---------------- wave helpers (wave64) ----------------
__device__ __forceinline__ float waveAllSum(float v) {
#pragma unroll
    for (int m = 32; m > 0; m >>= 1) v += __shfl_xor(v, m, 64);
    return v;
}
__device__ __forceinline__ float waveAllMax(float v) {
#pragma unroll
    for (int m = 32; m > 0; m >>= 1) v = fmaxf(v, __shfl_xor(v, m, 64));
    return v;
}
__device__ __forceinline__ float dot4(float4 a, float4 b, float acc) {
    acc = fmaf(a.x, b.x, acc);
    acc = fmaf(a.y, b.y, acc);
    acc = fmaf(a.z, b.z, acc);
    acc = fmaf(a.w, b.w, acc);
    return acc;
}

// ---------------- device-wide barrier (all NB blocks co-resident) ----------------
// bar layout (u32): [0]=generation, [8]=root counter, [32 + leaf*32]=leaf counters
__device__ __forceinline__ void grid_barrier(uint* bar, int bid) {
    __syncthreads();
    if (threadIdx.x == 0) {
        __threadfence();  // make this block's global writes device-visible
        uint* gen  = bar;
        uint* root = bar + 8;
        uint* leaf = bar + 32 + (bid & (NLEAF - 1)) * 32;
        uint g = __hip_atomic_load(gen, __ATOMIC_RELAXED, __HIP_MEMORY_SCOPE_AGENT);
        bool release_all = false;
        uint la = __hip_atomic_fetch_add(leaf, 1u, __ATOMIC_ACQ_REL, __HIP_MEMORY_SCOPE_AGENT);
        if (la == LEAF_N - 1) {
            __hip_atomic_store(leaf, 0u, __ATOMIC_RELAXED, __HIP_MEMORY_SCOPE_AGENT);
            uint ra = __hip_atomic_fetch_add(root, 1u, __ATOMIC_ACQ_REL, __HIP_MEMORY_SCOPE_AGENT);
            if (ra == NLEAF - 1) {
                __hip_atomic_store(root, 0u, __ATOMIC_RELAXED, __HIP_MEMORY_SCOPE_AGENT);
                __hip_atomic_store(gen, g + 1u, __ATOMIC_RELEASE, __HIP_MEMORY_SCOPE_AGENT);
                release_all = true;
            }
        }
        if (!release_all) {
            while (__hip_atomic_load(gen, __ATOMIC_ACQUIRE, __HIP_MEMORY_SCOPE_AGENT) == g)
                __builtin_amdgcn_s_sleep(2);
        }
        __threadfence();
    }
    __syncthreads();
}

// normalized x (h * rsqrt(mean(h^2)+eps) * nw) into xs[2048]; red = 8-float scratch
__device__ __forceinline__ void block_norm(const float* __restrict__ h,
                                           const float* __restrict__ nw,
                                           float* xs, float* red) {
    const int tid = threadIdx.x;
    const int lane = tid & 63, wid = tid >> 6;
    float4 a = ((const float4*)h)[tid];  // 512 threads * 4 = 2048
    float ss = a.x * a.x + a.y * a.y + a.z * a.z + a.w * a.w;
    ss = waveAllSum(ss);
    if (lane == 0) red[wid] = ss;
    __syncthreads();
    float tot = 0.f;
#pragma unroll
    for (int i = 0; i < 8; ++i) tot += red[i];
    const float f = rsqrtf(tot * (1.0f / (float)HID) + RMS_EPS);
    float4 n = ((const float4*)nw)[tid];
    ((float4*)xs)[tid] = make_float4(a.x * f * n.x, a.y * f * n.y,
                                     a.z * f * n.z, a.w * f * n.w);
    __syncthreads();
}

// ---------------- init: zero barrier state, h = x ----------------
__global__ __launch_bounds__(512) void k_init(const float* __restrict__ x,
                                              float* __restrict__ ws) {
    uint* bar = (uint*)ws;
#pragma unroll
    for (int k = 0; k < 4; ++k) bar[k * 512 + threadIdx.x] = 0u;
    float* h = ws + 2048;
#pragma unroll
    for (int k = 0; k < 4; ++k) h[k * 512 + threadIdx.x] = x[k * 512 + threadIdx.x];
}

// ---------------- the whole backbone, persistent ----------------
__global__ __launch_bounds__(NT, 4) void k_backbone(
    const float* __restrict__ kvw,
    const float* __restrict__ n1w, const float* __restrict__ n2w,
    const float* __restrict__ q_w, const float* __restrict__ o_w,
    const float* __restrict__ shg_w,
    const float* __restrict__ g_w, const float* __restrict__ u_w,
    const float* __restrict__ dn_w,
    float* __restrict__ out, float* __restrict__ ws) {
    __shared__ float lds[5760];

    uint* bar    = (uint*)ws;
    float* h     = ws + 2048;
    float* qv    = ws + 4096;
    float* ctx   = ws + 6144;
    float* inter = ws + 8192;          // 5632
    float* gsc   = ws + 8192 + 5632;   // 1 float

    const int bid = blockIdx.x;
    const int tid = threadIdx.x;
    const int lane = tid & 63, wid = tid >> 6;

    for (int L = 0; L < NL; ++L) {
        const float* Wq = q_w  + (size_t)L * HID * HID;
        const float* Wo = o_w  + (size_t)L * HID * HID;
        const float* Wg = g_w  + (size_t)L * INTER * HID;
        const float* Wu = u_w  + (size_t)L * INTER * HID;
        const float* Wd = dn_w + (size_t)L * HID * INTER;

        // ---- P1: qv = Wq @ rmsnorm(h, n1). 4 rows/block, half-row per wave ----
        {
            float* xn = lds;
            float* red = lds + 2048;
            float* part = lds + 2120;
            block_norm(h, n1w + L * HID, xn, red);
            const int row = bid * 4 + (wid >> 1);
            const int half = wid & 1;
            const float4* Wr = (const float4*)(Wq + (size_t)row * HID + half * 1024);
            const float4* X4 = (const float4*)(xn + half * 1024);
            float acc = 0.f;
#pragma unroll
            for (int k = 0; k < 4; ++k) acc = dot4(Wr[k * 64 + lane], X4[k * 64 + lane], acc);
            acc = waveAllSum(acc);
            if (lane == 0) part[wid] = acc;
            __syncthreads();
            if (tid < 4) qv[bid * 4 + tid] = part[2 * tid] + part[2 * tid + 1];
        }
        grid_barrier(bar, bid);

        // ---- P2: scores + softmax + ctx, blocks 0..31 only ----
        if (bid < 32) {
            float* ql   = lds;          // 2048
            float* sarr = lds + 2048;   // 8*256
            float* pj   = lds + 4096;   // 256
            float* redm = lds + 4352;   // 8
            float* reds = lds + 4360;   // 8
            ((float4*)ql)[tid] = ((const float4*)qv)[tid];
            __syncthreads();
            const float4* kv4 = (const float4*)kvw;
            float4 a4 = make_float4(0.f, 0.f, 0.f, 0.f);
            for (int r = 0; r < 256; ++r) {
                const int i = wid * 256 + r;
                const float qi = ql[i];
                const float4 kv = kv4[i * 64 + lane];
                a4.x = fmaf(qi, kv.x, a4.x);
                a4.y = fmaf(qi, kv.y, a4.y);
                a4.z = fmaf(qi, kv.z, a4.z);
                a4.w = fmaf(qi, kv.w, a4.w);
            }
            ((float4*)sarr)[wid * 64 + lane] = a4;
            __syncthreads();
            float s = 0.f;
            if (tid < 256) {
#pragma unroll
                for (int w = 0; w < 8; ++w) s += sarr[w * 256 + tid];
            }
            float m = waveAllMax(s);
            if (lane == 0) redm[wid] = m;
            __syncthreads();
            m = fmaxf(fmaxf(redm[0], redm[1]), fmaxf(redm[2], redm[3]));
            const float e = (tid < 256) ? __expf(s - m) : 0.f;
            float ts = waveAllSum(e);
            if (lane == 0) reds[wid] = ts;
            __syncthreads();
            const float denom = reds[0] + reds[1] + reds[2] + reds[3];
            if (tid < 256) pj[tid] = e / denom;
            __syncthreads();
            const float4* p4 = (const float4*)pj;
#pragma unroll
            for (int r = 0; r < 8; ++r) {
                const int i2 = bid * 64 + wid * 8 + r;
                float a = dot4(kv4[i2 * 64 + lane], p4[lane], 0.f);
                a = waveAllSum(a);
                if (lane == 0) ctx[i2] = a;
            }
        }
        grid_barrier(bar, bid);

        // ---- P3: h[row] += Wo[row,:] @ ctx ----
        {
            float* xb = lds;
            float* part = lds + 2120;
            ((float4*)xb)[tid] = ((const float4*)ctx)[tid];
            __syncthreads();
            const int row = bid * 4 + (wid >> 1);
            const int half = wid & 1;
            const float4* Wr = (const float4*)(Wo + (size_t)row * HID + half * 1024);
            const float4* X4 = (const float4*)(xb + half * 1024);
            float acc = 0.f;
#pragma unroll
            for (int k = 0; k < 4; ++k) acc = dot4(Wr[k * 64 + lane], X4[k * 64 + lane], acc);
            acc = waveAllSum(acc);
            if (lane == 0) part[wid] = acc;
            __syncthreads();
            if (tid < 4) {
                const int r = bid * 4 + tid;
                h[r] = h[r] + part[2 * tid] + part[2 * tid + 1];
            }
        }
        grid_barrier(bar, bid);

        // ---- P4: inter[j] = silu(Wg@x2)*(Wu@x2), 11 rows/block; block NB-1 also gate scalar ----
        {
            float* x2  = lds;           // 2048
            float* res = lds + 2048;    // 22
            float* red = lds + 2080;    // 8 (block_norm scratch)
            float* rg  = lds + 2088;    // 8 (gate scalar scratch)
            block_norm(h, n2w + L * HID, x2, red);
            const float4* X4 = (const float4*)x2;
            for (int t = wid; t < 22; t += 8) {
                const int j = bid * 11 + (t >> 1);
                const float* Wrow = ((t & 1) ? Wu : Wg) + (size_t)j * HID;
                const float4* Wr = (const float4*)Wrow;
                float acc = 0.f;
#pragma unroll
                for (int k = 0; k < 8; ++k) acc = dot4(Wr[k * 64 + lane], X4[k * 64 + lane], acc);
                acc = waveAllSum(acc);
                if (lane == 0) res[t] = acc;
            }
            if (bid == NB - 1) {
                const float4 w4 = ((const float4*)(shg_w + L * HID))[tid];
                const float4 xv = ((const float4*)x2)[tid];
                float pv = w4.x * xv.x + w4.y * xv.y + w4.z * xv.z + w4.w * xv.w;
                pv = waveAllSum(pv);
                if (lane == 0) rg[wid] = pv;
            }
            __syncthreads();
            if (tid < 11) {
                const float gv = res[2 * tid], uv = res[2 * tid + 1];
                inter[bid * 11 + tid] = (gv / (1.f + __expf(-gv))) * uv;
            }
            if (bid == NB - 1 && tid == 0) {
                float gl = 0.f;
#pragma unroll
                for (int i = 0; i < 8; ++i) gl += rg[i];
                gsc[0] = 1.f / (1.f + __expf(-gl));
            }
        }
        grid_barrier(bar, bid);

        // ---- P5: h[row] += g * (Wd[row,:] @ inter); last layer writes out ----
        {
            float* iL = lds;            // 5632
            float* part = lds + 5696;   // 8
#pragma unroll
            for (int k = 0; k < 11; ++k) iL[k * 512 + tid] = inter[k * 512 + tid];
            __syncthreads();
            const float g = gsc[0];
            const int row = bid * 4 + (wid >> 1);
            const int half = wid & 1;
            const float4* Dr = (const float4*)(Wd + (size_t)row * INTER + half * 2816);
            const float4* I4 = (const float4*)(iL + half * 2816);
            float acc = 0.f;
#pragma unroll
            for (int k = 0; k < 11; ++k) acc = dot4(Dr[k * 64 + lane], I4[k * 64 + lane], acc);
            acc = waveAllSum(acc);
            if (lane == 0) part[wid] = acc;
            __syncthreads();
            if (tid < 4) {
                const int r = bid * 4 + tid;
                const float v = h[r] + g * (part[2 * tid] + part[2 * tid + 1]);
                if (L == NL - 1) out[r] = v;
                else h[r] = v;
            }
        }
        if (L < NL - 1) grid_barrier(bar, bid);
    }
}

// ---------------- host ----------------
extern "C" void kernel_launch(void* const* d_in, const int* in_sizes, int n_in,
                              void* d_out, int out_size, void* d_ws, size_t ws_size,
                              hipStream_t stream) {
    const float* x     = (const float*)d_in[0];
    const float* kvw   = (const float*)d_in[1];
    const float* n1w   = (const float*)d_in[2];
    const float* n2w   = (const float*)d_in[3];
    const float* q_w   = (const float*)d_in[4];
    // d_in[5]=k_w, d_in[6]=v_w: dead in reference
    const float* o_w   = (const float*)d_in[7];
    // d_in[8]=router_w: dead
    const float* shg_w = (const float*)d_in[9];
    const float* g_w   = (const float*)d_in[10];
    const float* u_w   = (const float*)d_in[11];
    const float* dn_w  = (const float*)d_in[12];
    float* out = (float*)d_out;
    float* ws  = (float*)d_ws;

    k_init<<<1, 512, 0, stream>>>(x, ws);
    k_backbone<<<NB, NT, 0, stream>>>(kvw, n1w, n2w, q_w, o_w, shg_w,
                                      g_w, u_w, dn_w, out, ws);
}

// Round 3
// 453.063 us; speedup vs baseline: 9.8119x; 9.8119x over previous
//
#include <hip/hip_runtime.h>

#define HID 2048
#define INTER 5632
#define KVW 256
#define NL 6
#define RMS_EPS 1e-6f

#define NB 512     // 2 blocks per CU on 256 CUs -> guaranteed co-resident
#define NT 512     // 8 waves
#define NLEAF 32
#define LEAF_N 16  // NB / NLEAF

typedef unsigned int uint;

// ---- barrier state layout in d_ws (uint units) ----
#define BSTRIDE 64        // 256B between counters (separate cachelines)
#define ROOT_OFF 2048
#define GEN0 2112
#define NGENREP 16
#define MROOT 3136
#define MGEN0 3200
#define NMGEN 8
#define BAR_UINTS 4096

// ---------------- LLC (sc1) access: relaxed agent-scope atomics ----------------
// No acquire/release => no buffer_inv / buffer_wbl2 cache ops. Data moves via
// the coherent memory-side Infinity Cache; XCD L2s are bypassed for these.
__device__ __forceinline__ float ld_llc(const float* p) {
    return __hip_atomic_load(p, __ATOMIC_RELAXED, __HIP_MEMORY_SCOPE_AGENT);
}
__device__ __forceinline__ void st_llc(float* p, float v) {
    __hip_atomic_store(p, v, __ATOMIC_RELAXED, __HIP_MEMORY_SCOPE_AGENT);
}
__device__ __forceinline__ uint ld_llc_u(const uint* p) {
    return __hip_atomic_load(p, __ATOMIC_RELAXED, __HIP_MEMORY_SCOPE_AGENT);
}
__device__ __forceinline__ void st_llc_u(uint* p, uint v) {
    __hip_atomic_store(p, v, __ATOMIC_RELAXED, __HIP_MEMORY_SCOPE_AGENT);
}

// ---------------- wave helpers (wave64) ----------------
__device__ __forceinline__ float waveAllSum(float v) {
#pragma unroll
    for (int m = 32; m > 0; m >>= 1) v += __shfl_xor(v, m, 64);
    return v;
}
__device__ __forceinline__ float waveAllMax(float v) {
#pragma unroll
    for (int m = 32; m > 0; m >>= 1) v = fmaxf(v, __shfl_xor(v, m, 64));
    return v;
}
__device__ __forceinline__ float dot4(float4 a, float4 b, float acc) {
    acc = fmaf(a.x, b.x, acc);
    acc = fmaf(a.y, b.y, acc);
    acc = fmaf(a.z, b.z, acc);
    acc = fmaf(a.w, b.w, acc);
    return acc;
}

// ---------------- fence-free monotonic grid barrier ----------------
// __syncthreads() drains every wave's vmcnt before s_barrier, so all of this
// block's sc1 data stores are at the LLC before thread 0 issues the arrival
// add. Visibility chains through LLC serialization: gen observed => root add
// complete => all leaf adds complete => all data stores complete. Poll loads
// are RELAXED (no invalidate per iteration — round-2's fatal flaw).
__device__ __forceinline__ void grid_barrier(uint* bar, int bid, uint phase) {
    __syncthreads();
    if (threadIdx.x == 0) {
        uint* leaf = bar + (bid & (NLEAF - 1)) * BSTRIDE;
        uint la = __hip_atomic_fetch_add(leaf, 1u, __ATOMIC_RELAXED, __HIP_MEMORY_SCOPE_AGENT);
        if (la == phase * LEAF_N + (LEAF_N - 1)) {
            uint ra = __hip_atomic_fetch_add(bar + ROOT_OFF, 1u, __ATOMIC_RELAXED, __HIP_MEMORY_SCOPE_AGENT);
            if (ra == phase * NLEAF + (NLEAF - 1)) {
#pragma unroll
                for (int i = 0; i < NGENREP; ++i)
                    st_llc_u(bar + GEN0 + i * BSTRIDE, phase + 1u);
            }
        }
        const uint* myGen = bar + GEN0 + (bid & (NGENREP - 1)) * BSTRIDE;
        while (ld_llc_u(myGen) <= phase) __builtin_amdgcn_s_sleep(8);
    }
    __syncthreads();
}

// 32-block mini-barrier (blocks 0..31 only), same monotonic scheme
__device__ __forceinline__ void mini_barrier(uint* bar, int bid, uint mphase) {
    __syncthreads();
    if (threadIdx.x == 0) {
        uint ra = __hip_atomic_fetch_add(bar + MROOT, 1u, __ATOMIC_RELAXED, __HIP_MEMORY_SCOPE_AGENT);
        if (ra == mphase * 32u + 31u) {
#pragma unroll
            for (int i = 0; i < NMGEN; ++i)
                st_llc_u(bar + MGEN0 + i * BSTRIDE, mphase + 1u);
        }
        const uint* myGen = bar + MGEN0 + (bid & (NMGEN - 1)) * BSTRIDE;
        while (ld_llc_u(myGen) <= mphase) __builtin_amdgcn_s_sleep(4);
    }
    __syncthreads();
}

// ---------------- init: zero barrier state, h = x ----------------
__global__ __launch_bounds__(512) void k_init(const float* __restrict__ x,
                                              float* __restrict__ ws) {
    uint* bar = (uint*)ws;
#pragma unroll
    for (int k = 0; k < 8; ++k) bar[k * 512 + threadIdx.x] = 0u;
    float* h = ws + BAR_UINTS;
#pragma unroll
    for (int k = 0; k < 4; ++k) h[k * 512 + threadIdx.x] = x[k * 512 + threadIdx.x];
}

// ---------------- the whole backbone, persistent ----------------
__global__ __launch_bounds__(NT, 4) void k_backbone(
    const float* __restrict__ kvw,
    const float* __restrict__ n1w, const float* __restrict__ n2w,
    const float* __restrict__ q_w, const float* __restrict__ o_w,
    const float* __restrict__ shg_w,
    const float* __restrict__ g_w, const float* __restrict__ u_w,
    const float* __restrict__ dn_w,
    float* __restrict__ out, float* __restrict__ ws) {
    __shared__ float lds[5760];

    uint* bar      = (uint*)ws;
    float* h       = ws + BAR_UINTS;            // 2048
    float* qv      = ws + BAR_UINTS + 2048;     // 2048
    float* ctx     = ws + BAR_UINTS + 4096;     // 2048
    float* partial = ws + BAR_UINTS + 6144;     // 32*256 = 8192
    float* inter   = ws + BAR_UINTS + 14336;    // 5632
    float* gsc     = ws + BAR_UINTS + 19968;    // 1

    const int bid = blockIdx.x;
    const int tid = threadIdx.x;
    const int lane = tid & 63, wid = tid >> 6;
    uint gp = 0, mp = 0;

    for (int L = 0; L < NL; ++L) {
        const float* Wq = q_w  + (size_t)L * HID * HID;
        const float* Wo = o_w  + (size_t)L * HID * HID;
        const float* Wg = g_w  + (size_t)L * INTER * HID;
        const float* Wu = u_w  + (size_t)L * INTER * HID;
        const float* Wd = dn_w + (size_t)L * HID * INTER;

        // ---- P1: qv = Wq @ rmsnorm(h, n1). 4 rows/block, half-row per wave ----
        {
            float* xn = lds;            // 2048
            float* red = lds + 2048;    // 8
            float* part = lds + 2112;   // 8
            float hv[4];
            float ss = 0.f;
#pragma unroll
            for (int k = 0; k < 4; ++k) { hv[k] = ld_llc(h + k * 512 + tid); ss += hv[k] * hv[k]; }
            ss = waveAllSum(ss);
            if (lane == 0) red[wid] = ss;
            __syncthreads();
            float tot = 0.f;
#pragma unroll
            for (int i = 0; i < 8; ++i) tot += red[i];
            const float f = rsqrtf(tot * (1.0f / (float)HID) + RMS_EPS);
            const float* nw = n1w + L * HID;
#pragma unroll
            for (int k = 0; k < 4; ++k) xn[k * 512 + tid] = hv[k] * f * nw[k * 512 + tid];
            __syncthreads();
            const int row = bid * 4 + (wid >> 1);
            const int half = wid & 1;
            const float4* Wr = (const float4*)(Wq + (size_t)row * HID + half * 1024);
            const float4* X4 = (const float4*)(xn + half * 1024);
            float acc = 0.f;
#pragma unroll
            for (int k = 0; k < 4; ++k) acc = dot4(Wr[k * 64 + lane], X4[k * 64 + lane], acc);
            acc = waveAllSum(acc);
            if (lane == 0) part[wid] = acc;
            __syncthreads();
            if (tid < 4) st_llc(qv + bid * 4 + tid, part[2 * tid] + part[2 * tid + 1]);
        }
        grid_barrier(bar, bid, gp++);

        // ---- P2: attention, blocks 0..31; others sleep at next barrier ----
        if (bid < 32) {
            // P2a: partial scores for this block's 64-row strip of kvw
            {
                float* qs = lds;          // 64
                float* ps = lds + 64;     // 512
                if (tid < 64) qs[tid] = ld_llc(qv + bid * 64 + tid);
                __syncthreads();
                const int j = tid & 255;
                const int ihalf = tid >> 8;
                const float* kvbase = kvw + ((size_t)bid * 64 + ihalf * 32) * KVW;
                float acc = 0.f;
#pragma unroll 8
                for (int r = 0; r < 32; ++r)
                    acc = fmaf(qs[ihalf * 32 + r], kvbase[(size_t)r * KVW + j], acc);
                ps[ihalf * 256 + j] = acc;
                __syncthreads();
                if (tid < 256) st_llc(partial + bid * 256 + tid, ps[tid] + ps[256 + tid]);
            }
            mini_barrier(bar, bid, mp++);
            // P2b: reduce partials, softmax, ctx rows for this strip
            {
                float* pj = lds;          // 256
                float* red = lds + 256;   // 8
                float s = 0.f;
                if (tid < 256) {
#pragma unroll 8
                    for (int b = 0; b < 32; ++b) s += ld_llc(partial + b * 256 + tid);
                }
                float m = waveAllMax((tid < 256) ? s : -3.4e38f);
                if (lane == 0) red[wid] = m;
                __syncthreads();
                m = fmaxf(fmaxf(red[0], red[1]), fmaxf(red[2], red[3]));
                const float e = (tid < 256) ? __expf(s - m) : 0.f;
                __syncthreads();
                float t = waveAllSum(e);
                if (lane == 0) red[wid] = t;
                __syncthreads();
                const float denom = red[0] + red[1] + red[2] + red[3];
                if (tid < 256) pj[tid] = e / denom;
                __syncthreads();
                const float4* p4 = (const float4*)pj;
                const float4* kv4 = (const float4*)kvw;
#pragma unroll
                for (int r = 0; r < 8; ++r) {
                    const int i = bid * 64 + wid * 8 + r;
                    float a = dot4(kv4[(size_t)i * 64 + lane], p4[lane], 0.f);
                    a = waveAllSum(a);
                    if (lane == 0) st_llc(ctx + i, a);
                }
            }
        }
        grid_barrier(bar, bid, gp++);

        // ---- P3: h[row] += Wo[row,:] @ ctx ----
        {
            float* xb = lds;            // 2048
            float* part = lds + 2112;   // 8
#pragma unroll
            for (int k = 0; k < 4; ++k) xb[k * 512 + tid] = ld_llc(ctx + k * 512 + tid);
            __syncthreads();
            const int row = bid * 4 + (wid >> 1);
            const int half = wid & 1;
            const float4* Wr = (const float4*)(Wo + (size_t)row * HID + half * 1024);
            const float4* X4 = (const float4*)(xb + half * 1024);
            float acc = 0.f;
#pragma unroll
            for (int k = 0; k < 4; ++k) acc = dot4(Wr[k * 64 + lane], X4[k * 64 + lane], acc);
            acc = waveAllSum(acc);
            if (lane == 0) part[wid] = acc;
            __syncthreads();
            if (tid < 4) {
                const int r = bid * 4 + tid;
                st_llc(h + r, ld_llc(h + r) + part[2 * tid] + part[2 * tid + 1]);
            }
        }
        grid_barrier(bar, bid, gp++);

        // ---- P4: inter = silu(Wg@x2)*(Wu@x2); block NB-1 also the scalar gate ----
        {
            float* x2 = lds;            // 2048
            float* res = lds + 2048;    // 22
            float* red = lds + 2080;    // 8
            float* rg  = lds + 2092;    // 8
            float hv[4];
            float ss = 0.f;
#pragma unroll
            for (int k = 0; k < 4; ++k) { hv[k] = ld_llc(h + k * 512 + tid); ss += hv[k] * hv[k]; }
            ss = waveAllSum(ss);
            if (lane == 0) red[wid] = ss;
            __syncthreads();
            float tot = 0.f;
#pragma unroll
            for (int i = 0; i < 8; ++i) tot += red[i];
            const float f = rsqrtf(tot * (1.0f / (float)HID) + RMS_EPS);
            const float* nw = n2w + L * HID;
#pragma unroll
            for (int k = 0; k < 4; ++k) x2[k * 512 + tid] = hv[k] * f * nw[k * 512 + tid];
            __syncthreads();
            const float4* X4 = (const float4*)x2;
            for (int t = wid; t < 22; t += 8) {
                const int jj = bid * 11 + (t >> 1);
                const float4* Wr = (const float4*)(((t & 1) ? Wu : Wg) + (size_t)jj * HID);
                float acc = 0.f;
#pragma unroll
                for (int k = 0; k < 8; ++k) acc = dot4(Wr[k * 64 + lane], X4[k * 64 + lane], acc);
                acc = waveAllSum(acc);
                if (lane == 0) res[t] = acc;
            }
            if (bid == NB - 1) {
                const float* sw = shg_w + L * HID;
                float pv = 0.f;
#pragma unroll
                for (int k = 0; k < 4; ++k) pv += sw[k * 512 + tid] * x2[k * 512 + tid];
                pv = waveAllSum(pv);
                if (lane == 0) rg[wid] = pv;
            }
            __syncthreads();
            if (tid < 11) {
                const float gv = res[2 * tid], uv = res[2 * tid + 1];
                st_llc(inter + bid * 11 + tid, (gv / (1.f + __expf(-gv))) * uv);
            }
            if (bid == NB - 1 && tid == 0) {
                float gl = 0.f;
#pragma unroll
                for (int i = 0; i < 8; ++i) gl += rg[i];
                st_llc(gsc, 1.f / (1.f + __expf(-gl)));
            }
        }
        grid_barrier(bar, bid, gp++);

        // ---- P5: h[row] += g * (Wd[row,:] @ inter); last layer -> out ----
        {
            float* iL = lds;            // 5632
            float* part = lds + 5696;   // 8
#pragma unroll
            for (int k = 0; k < 11; ++k) iL[k * 512 + tid] = ld_llc(inter + k * 512 + tid);
            __syncthreads();
            const float g = ld_llc(gsc);
            const int row = bid * 4 + (wid >> 1);
            const int half = wid & 1;
            const float4* Dr = (const float4*)(Wd + (size_t)row * INTER + half * 2816);
            const float4* I4 = (const float4*)(iL + half * 2816);
            float acc = 0.f;
#pragma unroll
            for (int k = 0; k < 11; ++k) acc = dot4(Dr[k * 64 + lane], I4[k * 64 + lane], acc);
            acc = waveAllSum(acc);
            if (lane == 0) part[wid] = acc;
            __syncthreads();
            if (tid < 4) {
                const int r = bid * 4 + tid;
                const float v = ld_llc(h + r) + g * (part[2 * tid] + part[2 * tid + 1]);
                if (L == NL - 1) out[r] = v;
                else st_llc(h + r, v);
            }
        }
        if (L < NL - 1) grid_barrier(bar, bid, gp++);
    }
}

// ---------------- host ----------------
extern "C" void kernel_launch(void* const* d_in, const int* in_sizes, int n_in,
                              void* d_out, int out_size, void* d_ws, size_t ws_size,
                              hipStream_t stream) {
    const float* x     = (const float*)d_in[0];
    const float* kvw   = (const float*)d_in[1];
    const float* n1w   = (const float*)d_in[2];
    const float* n2w   = (const float*)d_in[3];
    const float* q_w   = (const float*)d_in[4];
    // d_in[5]=k_w, d_in[6]=v_w: dead in reference
    const float* o_w   = (const float*)d_in[7];
    // d_in[8]=router_w: dead
    const float* shg_w = (const float*)d_in[9];
    const float* g_w   = (const float*)d_in[10];
    const float* u_w   = (const float*)d_in[11];
    const float* dn_w  = (const float*)d_in[12];
    float* out = (float*)d_out;
    float* ws  = (float*)d_ws;

    k_init<<<1, 512, 0, stream>>>(x, ws);
    k_backbone<<<NB, NT, 0, stream>>>(kvw, n1w, n2w, q_w, o_w, shg_w,
                                      g_w, u_w, dn_w, out, ws);
}

// Round 4
// 432.364 us; speedup vs baseline: 10.2817x; 1.0479x over previous
//
#include <hip/hip_runtime.h>

#define HID 2048
#define INTER 5632
#define KVW 256
#define NL 6
#define RMS_EPS 1e-6f

#define NB 256     // 1 block per CU (VGPR 65..128 forces exclusivity)
#define NT 1024    // 16 waves

typedef unsigned int uint;

// ws layout: uint region [0, 2048) = barriers; floats after.
#define F_H     2048
#define F_QV    4096
#define F_CTX   6144
#define F_PART  8192     // 32*256
#define F_INTER 16384    // 5632
#define F_GSC   22016

// ---------------- LLC (relaxed agent-scope) access ----------------
__device__ __forceinline__ float ld_llc(const float* p) {
    return __hip_atomic_load(p, __ATOMIC_RELAXED, __HIP_MEMORY_SCOPE_AGENT);
}
__device__ __forceinline__ void st_llc(float* p, float v) {
    __hip_atomic_store(p, v, __ATOMIC_RELAXED, __HIP_MEMORY_SCOPE_AGENT);
}

// ---------------- wave helpers ----------------
__device__ __forceinline__ float waveAllSum(float v) {
#pragma unroll
    for (int m = 32; m > 0; m >>= 1) v += __shfl_xor(v, m, 64);
    return v;
}
__device__ __forceinline__ float waveAllMax(float v) {
#pragma unroll
    for (int m = 32; m > 0; m >>= 1) v = fmaxf(v, __shfl_xor(v, m, 64));
    return v;
}
__device__ __forceinline__ float dot4(float4 a, float4 b, float acc) {
    acc = fmaf(a.x, b.x, acc);
    acc = fmaf(a.y, b.y, acc);
    acc = fmaf(a.z, b.z, acc);
    acc = fmaf(a.w, b.w, acc);
    return acc;
}

// ---------------- flat monotonic barrier (2 LLC round trips) ----------------
// Arrivals: +1 on one of (mask+1) spread cachelines. Waiters: wave 0 reads all
// lines in ONE vector load, shuffle-reduces; redundancy 64/(mask+1) scales the
// target. Monotonic counters, no reset, no fences: __syncthreads drains vmcnt
// before the arrival add, so prior sc1 data stores are at the LLC first.
__device__ __forceinline__ void bar_arrive(uint* base, int line) {
    __syncthreads();
    if (threadIdx.x == 0)
        __hip_atomic_fetch_add(base + line * 64, 1u, __ATOMIC_RELAXED, __HIP_MEMORY_SCOPE_AGENT);
}
__device__ __forceinline__ void bar_wait(const uint* base, int mask, uint target) {
    if (threadIdx.x < 64) {
        const uint* p = base + (threadIdx.x & mask) * 64;
        while (true) {
            uint v = __hip_atomic_load(p, __ATOMIC_RELAXED, __HIP_MEMORY_SCOPE_AGENT);
#pragma unroll
            for (int m = 32; m > 0; m >>= 1) v += __shfl_xor(v, m, 64);
            if (v >= target) break;
            __builtin_amdgcn_s_sleep(1);
        }
    }
    __syncthreads();
}

// rmsnorm(h, nw) -> xbuf[2048] (LDS); aux[0..16) scratch
__device__ __forceinline__ void block_rms_norm(const float* __restrict__ h,
                                               const float* __restrict__ nw,
                                               float* xbuf, float* aux) {
    const int tid = threadIdx.x, lane = tid & 63, wid = tid >> 6;
    const float a = ld_llc(h + 2 * tid), b = ld_llc(h + 2 * tid + 1);
    float ss = a * a + b * b;
    ss = waveAllSum(ss);
    if (lane == 0) aux[wid] = ss;
    __syncthreads();
    float tot = 0.f;
#pragma unroll
    for (int i = 0; i < 16; ++i) tot += aux[i];
    const float f = rsqrtf(tot * (1.0f / (float)HID) + RMS_EPS);
    xbuf[2 * tid]     = a * f * nw[2 * tid];
    xbuf[2 * tid + 1] = b * f * nw[2 * tid + 1];
    __syncthreads();
}

// ---------------- init ----------------
__global__ __launch_bounds__(1024) void k_init(const float* __restrict__ x,
                                               float* __restrict__ ws) {
    uint* bar = (uint*)ws;
    bar[threadIdx.x] = 0u;
    bar[1024 + threadIdx.x] = 0u;
    float* h = ws + F_H;
    h[threadIdx.x] = x[threadIdx.x];
    h[1024 + threadIdx.x] = x[1024 + threadIdx.x];
}

// ---------------- persistent backbone ----------------
__global__ __launch_bounds__(NT, 4) void k_backbone(
    const float* __restrict__ kvw,
    const float* __restrict__ n1w, const float* __restrict__ n2w,
    const float* __restrict__ q_w, const float* __restrict__ o_w,
    const float* __restrict__ shg_w,
    const float* __restrict__ g_w, const float* __restrict__ u_w,
    const float* __restrict__ dn_w,
    float* __restrict__ out, float* __restrict__ ws) {
    __shared__ float buf[5632];
    __shared__ float aux[64];

    uint*  gbar    = (uint*)ws;          // 16 lines
    uint*  mbar    = (uint*)ws + 1024;   // 8 lines
    float* h       = ws + F_H;
    float* qv      = ws + F_QV;
    float* ctx     = ws + F_CTX;
    float* partial = ws + F_PART;
    float* inter   = ws + F_INTER;
    float* gsc     = ws + F_GSC;

    const int bid  = blockIdx.x;
    const int tid  = threadIdx.x;
    const int lane = tid & 63, wid = tid >> 6;
    const int row8 = bid * 8 + (wid >> 1);   // this block's 8 hidden rows
    const int half = wid & 1;
    uint gp = 0, mp = 0;

    // prefetch layer-0 Wq rows
    float4 qpre[4];
    {
        const float4* Qn = (const float4*)(q_w + (size_t)row8 * HID + half * 1024);
#pragma unroll
        for (int k = 0; k < 4; ++k) qpre[k] = Qn[k * 64 + lane];
    }

    for (int L = 0; L < NL; ++L) {
        const float* Wo = o_w  + (size_t)L * HID * HID;
        const float* Wg = g_w  + (size_t)L * INTER * HID;
        const float* Wu = u_w  + (size_t)L * INTER * HID;
        const float* Wd = dn_w + (size_t)L * HID * INTER;

        // ---- P1: qv = Wq @ rmsnorm(h, n1) (weights already in registers) ----
        block_rms_norm(h, n1w + L * HID, buf, aux);
        {
            const float4* X4 = (const float4*)(buf + half * 1024);
            float acc = 0.f;
#pragma unroll
            for (int k = 0; k < 4; ++k) acc = dot4(qpre[k], X4[k * 64 + lane], acc);
            acc = waveAllSum(acc);
            if (lane == 0) aux[16 + wid] = acc;
            __syncthreads();
            if (tid < 8) st_llc(qv + bid * 8 + tid, aux[16 + 2 * tid] + aux[16 + 2 * tid + 1]);
        }
        // attention blocks prefetch their kvw strip scalars
        float kpre[16];
        const int j = tid & 255, q4 = tid >> 8;
        if (bid < 32) {
            const float* kb = kvw + ((size_t)(bid * 64 + q4 * 16)) * KVW + j;
#pragma unroll
            for (int r = 0; r < 16; ++r) kpre[r] = kb[r * KVW];
        }
        bar_arrive(gbar, bid & 15);
        bar_wait(gbar, 15, 1024u * (gp + 1)); ++gp;

        // ---- P2: attention on blocks 0..31 ----
        if (bid < 32) {
            // P2a: partial scores for this block's 64-row strip
            float* qs = buf;          // 64
            float* ps = buf + 64;     // 1024
            if (tid < 64) qs[tid] = ld_llc(qv + bid * 64 + tid);
            __syncthreads();
            float acc = 0.f;
#pragma unroll
            for (int r = 0; r < 16; ++r) acc = fmaf(qs[q4 * 16 + r], kpre[r], acc);
            ps[q4 * 256 + j] = acc;
            __syncthreads();
            if (tid < 256)
                st_llc(partial + bid * 256 + tid,
                       ps[tid] + ps[256 + tid] + ps[512 + tid] + ps[768 + tid]);
            bar_arrive(mbar, bid & 7);
            bar_wait(mbar, 7, 256u * (mp + 1)); ++mp;

            // P2b: reduce partials -> softmax -> ctx strip
            float* sp = buf;          // 1024
            float* pj = buf + 1024;   // 256
            {
                float s = 0.f;
#pragma unroll
                for (int b = 0; b < 8; ++b) s += ld_llc(partial + (q4 * 8 + b) * 256 + j);
                sp[q4 * 256 + j] = s;
            }
            __syncthreads();
            float sv = -3.4e38f;
            if (tid < 256) sv = sp[tid] + sp[256 + tid] + sp[512 + tid] + sp[768 + tid];
            float mx = waveAllMax(sv);
            if (lane == 0 && wid < 4) aux[wid] = mx;
            __syncthreads();
            mx = fmaxf(fmaxf(aux[0], aux[1]), fmaxf(aux[2], aux[3]));
            const float e = (tid < 256) ? __expf(sv - mx) : 0.f;
            float tsum = waveAllSum(e);
            if (lane == 0 && wid < 4) aux[8 + wid] = tsum;
            __syncthreads();
            const float den = aux[8] + aux[9] + aux[10] + aux[11];
            if (tid < 256) pj[tid] = e / den;
            __syncthreads();
            const float4* p4  = (const float4*)pj;
            const float4* kv4 = (const float4*)kvw;
#pragma unroll
            for (int r = 0; r < 4; ++r) {
                const int i = bid * 64 + wid * 4 + r;
                float a = dot4(kv4[(size_t)i * 64 + lane], p4[lane], 0.f);
                a = waveAllSum(a);
                if (lane == 0) st_llc(ctx + i, a);
            }
        }
        // all blocks: prefetch Wo rows + first gate/up row during the bubble
        float4 wo[4];
        {
            const float4* Wr = (const float4*)(Wo + (size_t)row8 * HID + half * 1024);
#pragma unroll
            for (int k = 0; k < 4; ++k) wo[k] = Wr[k * 64 + lane];
        }
        float4 g0[8];
        {
            const int jj = bid * 22 + (wid >> 1);
            const float4* Wr = (const float4*)(((wid & 1) ? Wu : Wg) + (size_t)jj * HID);
#pragma unroll
            for (int k = 0; k < 8; ++k) g0[k] = Wr[k * 64 + lane];
        }
        bar_arrive(gbar, bid & 15);
        bar_wait(gbar, 15, 1024u * (gp + 1)); ++gp;

        // ---- P3: h[row] += Wo[row,:] @ ctx (Wo prefetched) ----
        {
            buf[2 * tid]     = ld_llc(ctx + 2 * tid);
            buf[2 * tid + 1] = ld_llc(ctx + 2 * tid + 1);
            __syncthreads();
            const float4* X4 = (const float4*)(buf + half * 1024);
            float acc = 0.f;
#pragma unroll
            for (int k = 0; k < 4; ++k) acc = dot4(wo[k], X4[k * 64 + lane], acc);
            acc = waveAllSum(acc);
            if (lane == 0) aux[16 + wid] = acc;
            __syncthreads();
            if (tid < 8) {
                const int r = bid * 8 + tid;
                st_llc(h + r, ld_llc(h + r) + aux[16 + 2 * tid] + aux[16 + 2 * tid + 1]);
            }
        }
        bar_arrive(gbar, bid & 15);
        bar_wait(gbar, 15, 1024u * (gp + 1)); ++gp;

        // ---- P4: inter = silu(Wg@x2)*(Wu@x2); block 0 computes scalar gate ----
        block_rms_norm(h, n2w + L * HID, buf, aux);
        {
            float* res = buf + 2048;   // 44
            const float4* X4 = (const float4*)buf;
            {   // prefetched row t = wid
                float acc = 0.f;
#pragma unroll
                for (int k = 0; k < 8; ++k) acc = dot4(g0[k], X4[k * 64 + lane], acc);
                acc = waveAllSum(acc);
                if (lane == 0) res[wid] = acc;
            }
            for (int t = wid + 16; t < 44; t += 16) {   // stream remaining rows
                const int jj = bid * 22 + (t >> 1);
                const float4* Wr = (const float4*)(((t & 1) ? Wu : Wg) + (size_t)jj * HID);
                float acc = 0.f;
#pragma unroll
                for (int k = 0; k < 8; ++k) acc = dot4(Wr[k * 64 + lane], X4[k * 64 + lane], acc);
                acc = waveAllSum(acc);
                if (lane == 0) res[t] = acc;
            }
            if (bid == 0) {
                const float* sw = shg_w + L * HID;
                float pv = sw[2 * tid] * buf[2 * tid] + sw[2 * tid + 1] * buf[2 * tid + 1];
                pv = waveAllSum(pv);
                if (lane == 0) aux[32 + wid] = pv;
            }
            __syncthreads();
            if (tid < 22) {
                const float gv = res[2 * tid], uv = res[2 * tid + 1];
                st_llc(inter + bid * 22 + tid, gv / (1.f + __expf(-gv)) * uv);
            }
            if (bid == 0 && tid == 0) {
                float gl = 0.f;
#pragma unroll
                for (int i = 0; i < 16; ++i) gl += aux[32 + i];
                st_llc(gsc, 1.f / (1.f + __expf(-gl)));
            }
        }
        // prefetch the ENTIRE Wd chunk for this block (44 VGPRs)
        float4 dpre[11];
        {
            const float4* Dr = (const float4*)(Wd + (size_t)row8 * INTER + half * 2816);
#pragma unroll
            for (int k = 0; k < 11; ++k) dpre[k] = Dr[k * 64 + lane];
        }
        bar_arrive(gbar, bid & 15);
        bar_wait(gbar, 15, 1024u * (gp + 1)); ++gp;

        // ---- P5: h[row] += g * (Wd[row,:] @ inter) (Wd prefetched) ----
        {
#pragma unroll
            for (int k = 0; k < 6; ++k) {
                const int idx = k * 1024 + tid;
                if (idx < INTER) buf[idx] = ld_llc(inter + idx);
            }
            __syncthreads();
            const float gg = ld_llc(gsc);
            const float4* I4 = (const float4*)(buf + half * 2816);
            float acc = 0.f;
#pragma unroll
            for (int k = 0; k < 11; ++k) acc = dot4(dpre[k], I4[k * 64 + lane], acc);
            acc = waveAllSum(acc);
            if (lane == 0) aux[16 + wid] = acc;
            __syncthreads();
            if (tid < 8) {
                const int r = bid * 8 + tid;
                const float v = ld_llc(h + r) + gg * (aux[16 + 2 * tid] + aux[16 + 2 * tid + 1]);
                if (L == NL - 1) out[r] = v;
                else st_llc(h + r, v);
            }
        }
        if (L < NL - 1) {
            // prefetch next layer's Wq rows before the layer-end barrier
            const float4* Qn = (const float4*)(q_w + (size_t)(L + 1) * HID * HID +
                                               (size_t)row8 * HID + half * 1024);
#pragma unroll
            for (int k = 0; k < 4; ++k) qpre[k] = Qn[k * 64 + lane];
            bar_arrive(gbar, bid & 15);
            bar_wait(gbar, 15, 1024u * (gp + 1)); ++gp;
        }
    }
}

// ---------------- host ----------------
extern "C" void kernel_launch(void* const* d_in, const int* in_sizes, int n_in,
                              void* d_out, int out_size, void* d_ws, size_t ws_size,
                              hipStream_t stream) {
    const float* x     = (const float*)d_in[0];
    const float* kvw   = (const float*)d_in[1];
    const float* n1w   = (const float*)d_in[2];
    const float* n2w   = (const float*)d_in[3];
    const float* q_w   = (const float*)d_in[4];
    // d_in[5]=k_w, d_in[6]=v_w: dead in reference
    const float* o_w   = (const float*)d_in[7];
    // d_in[8]=router_w: dead
    const float* shg_w = (const float*)d_in[9];
    const float* g_w   = (const float*)d_in[10];
    const float* u_w   = (const float*)d_in[11];
    const float* dn_w  = (const float*)d_in[12];
    float* out = (float*)d_out;
    float* ws  = (float*)d_ws;

    k_init<<<1, 1024, 0, stream>>>(x, ws);
    k_backbone<<<NB, NT, 0, stream>>>(kvw, n1w, n2w, q_w, o_w, shg_w,
                                      g_w, u_w, dn_w, out, ws);
}